// Round 9
// baseline (285.342 us; speedup 1.0000x reference)
//
#include <hip/hip_runtime.h>
#include <hip/hip_bf16.h>
#include <cstdint>
#include <cstddef>

#define NB 2
#define NH 8
#define BHN 16          // NB*NH
#define NN 3072         // tokens
#define CC 256          // channels
#define DD 32           // head dim
#define OUTW 3104       // NN + DD
#define VW 48           // padded v2p width (38 -> 48)
#define KP 384          // NH*VW, padded K for proj GEMM

typedef __attribute__((ext_vector_type(8))) __bf16 bf16x8;
typedef __attribute__((ext_vector_type(4))) short short4v;
typedef __attribute__((ext_vector_type(4))) float f32x4;

static __device__ __forceinline__ unsigned short f2bf(float f) {
    __hip_bfloat16 h = __float2bfloat16(f);
    return *reinterpret_cast<unsigned short*>(&h);
}

static __device__ __forceinline__ bf16x8 ldb8(const unsigned short* p) {
    return *(const bf16x8*)p;
}

static __device__ __forceinline__ f32x4 mfma16(bf16x8 a, bf16x8 b, f32x4 c) {
    return __builtin_amdgcn_mfma_f32_16x16x32_bf16(a, b, c, 0, 0, 0);
}

static __device__ __forceinline__ float bfhi2f(unsigned u) {
    union { unsigned u; float f; } v; v.u = u & 0xffff0000u; return v.f;
}
static __device__ __forceinline__ float bflo2f(unsigned u) {
    union { unsigned u; float f; } v; v.u = u << 16; return v.f;
}

// ---------------------------------------------------------------------------
// prep
// ---------------------------------------------------------------------------
__global__ __launch_bounds__(256) void prep_kernel(
    const float* __restrict__ x1, const float* __restrict__ x2,
    const float* __restrict__ Wq, const float* __restrict__ Wkv,
    const float* __restrict__ Wpf,
    unsigned short* __restrict__ x1b, unsigned short* __restrict__ x2b,
    unsigned short* __restrict__ Wt, unsigned short* __restrict__ Wpft,
    unsigned short* __restrict__ v2pT)
{
    int i = blockIdx.x * 256 + threadIdx.x;
    const int S_X = NB * NN * CC;
    if (i < S_X) { x1b[i] = f2bf(x1[i]); return; }
    i -= S_X;
    if (i < S_X) { x2b[i] = f2bf(x2[i]); return; }
    i -= S_X;
    const int S_WT = 768 * CC;
    if (i < S_WT) {
        int j = i >> 8, kk = i & 255;
        float w = (j < 256) ? Wq[kk * 256 + j] : Wkv[kk * 512 + (j - 256)];
        Wt[i] = f2bf(w);
        return;
    }
    i -= S_WT;
    const int S_WP = 256 * KP;
    if (i < S_WP) {
        int c2 = i / KP, t = i - c2 * KP;
        int h = t / VW, cc = t - h * VW;
        unsigned short v = 0;
        if (cc < 38) v = f2bf(Wpf[(h * 38 + cc) * 256 + c2]);
        Wpft[i] = v;
        return;
    }
    i -= S_WP;
    const int S_POS = BHN * 16 * NN;
    if (i < S_POS) {
        int n = i % NN;
        int r = i / NN;
        int bh = r >> 4;
        int c = (r & 15) + 32;
        float val = 0.f;
        if (c < 38) {
            float p3 = -1.f + 2.f * (float)(n % 48) / 47.f;
            float p4 = -1.f + 2.f * (float)(n / 48) / 63.f;
            float pv[6] = { p3 * p3, p4 * p4, p3 * p4, p3, p4, 1.f };
            val = pv[c - 32];
        }
        v2pT[((size_t)bh * VW + c) * NN + n] = f2bf(val);
    }
}

// ---------------------------------------------------------------------------
// qkv
// ---------------------------------------------------------------------------
__global__ __launch_bounds__(256) void qkv_kernel(
    const unsigned short* __restrict__ x1b, const unsigned short* __restrict__ x2b,
    const unsigned short* __restrict__ Wt,
    unsigned short* __restrict__ qbh, unsigned short* __restrict__ kbh,
    unsigned short* __restrict__ v2pT)
{
    int rt = blockIdx.x, ct = blockIdx.y;
    int wv = threadIdx.x >> 6, lane = threadIdx.x & 63;
    int g = lane >> 4, q = lane & 15;
    int row0 = rt * 64 + wv * 16;
    const unsigned short* A = (ct < 4) ? x1b : x2b;
    const unsigned short* arow = A + (size_t)(row0 + q) * CC + g * 8;
    const unsigned short* brow = Wt + (size_t)(ct * 64 + q) * CC + g * 8;
    f32x4 acc[4];
    #pragma unroll
    for (int cb = 0; cb < 4; ++cb) acc[cb] = f32x4{0.f, 0.f, 0.f, 0.f};
    for (int k0 = 0; k0 < CC; k0 += 32) {
        bf16x8 af = ldb8(arow + k0);
        #pragma unroll
        for (int cb = 0; cb < 4; ++cb)
            acc[cb] = mfma16(af, ldb8(brow + (size_t)cb * 16 * CC + k0), acc[cb]);
    }
    int b = row0 / NN, nb = row0 % NN;
    #pragma unroll
    for (int cb = 0; cb < 4; ++cb) {
        int jj = ct * 64 + cb * 16 + q;
        #pragma unroll
        for (int r = 0; r < 4; ++r) {
            int n = nb + 4 * g + r;
            unsigned short bv = f2bf(acc[cb][r]);
            if (jj < 256) {
                int h = jj >> 5, c = jj & 31;
                qbh[(size_t)((b * NH + h) * NN + n) * DD + c] = bv;
            } else if (jj < 512) {
                int jk = jj - 256; int h = jk >> 5, c = jk & 31;
                kbh[(size_t)((b * NH + h) * NN + n) * DD + c] = bv;
            } else {
                int jv = jj - 512; int h = jv >> 5, c = jv & 31;
                v2pT[(size_t)((b * NH + h) * VW + c) * NN + n] = bv;
            }
        }
    }
}

// ---------------------------------------------------------------------------
// fused attention: identical to R7 (best structure) EXCEPT the store burst
// uses PLAIN CACHED stores instead of non-temporal. Theory: 1KB bursts fully
// cover 128B lines (no read-for-ownership), and the 4MB/XCD L2 acts as a
// write-combining buffer whose eviction stream presents HBM with long
// sequential runs — the same path that lets fillBufferAligned hit 6.6 TB/s.
// ---------------------------------------------------------------------------
__global__ __launch_bounds__(256) void attn_kernel(
    const unsigned short* __restrict__ qbh, const unsigned short* __restrict__ kbh,
    const unsigned short* __restrict__ v2pT,
    float* __restrict__ out, unsigned short* __restrict__ yacc)
{
    __shared__ unsigned short ptile[4][16][256];   // 32 KB, per-wave [16][256]
    const float C = 0.17677669529663687f * 1.4426950408889634f;  // scale*log2e

    // XCD-bijective swizzle (neutral, kept from R7): 768 % 8 == 0
    int id = blockIdx.x;
    int xcd = id & 7;
    int slot = id >> 3;                 // 0..95
    int bh = xcd * 2 + (slot & 1);      // 0..15
    int qt = slot >> 1;                 // 0..47

    int wv = threadIdx.x >> 6, lane = threadIdx.x & 63;
    int g = lane >> 4, q = lane & 15;
    int qrow = qt * 64 + wv * 16;

    bf16x8 qf = ldb8(qbh + (size_t)(bh * NN + qrow + q) * DD + g * 8);
    const unsigned short* kbase = kbh + (size_t)bh * NN * DD;
    const unsigned short* vbase = v2pT + (size_t)bh * VW * NN;

    // ---- pass A: row sums of exp ----
    float l = 0.f;
    {
        bf16x8 kf0 = ldb8(kbase + (size_t)(q) * DD + g * 8);
        bf16x8 kf1 = ldb8(kbase + (size_t)(16 + q) * DD + g * 8);
        for (int it = 0; it < 96; ++it) {
            int m0 = it * 32;
            bf16x8 kn0 = ldb8(kbase + (size_t)(m0 + 32 + q) * DD + g * 8);
            bf16x8 kn1 = ldb8(kbase + (size_t)(m0 + 48 + q) * DD + g * 8);
            f32x4 z = {0.f, 0.f, 0.f, 0.f};
            f32x4 s0 = mfma16(kf0, qf, z);
            f32x4 s1 = mfma16(kf1, qf, z);
            #pragma unroll
            for (int r = 0; r < 4; ++r)
                l += exp2f(s0[r] * C) + exp2f(s1[r] * C);
            kf0 = kn0; kf1 = kn1;
        }
    }
    l += __shfl_xor(l, 16, 64);
    l += __shfl_xor(l, 32, 64);
    float nl2 = -__log2f(l);                  // p = exp2(s*C + nl2)

    // ---- pass B ----
    f32x4 yt0 = {0.f,0.f,0.f,0.f}, yt1 = yt0, yt2 = yt0;
    char* myt = (char*)&ptile[wv][0][0];         // 16 rows x 512 B
    char* prow = myt + q * 512;                  // this thread's write row
    unsigned swq = (unsigned)((q & 7) << 4);     // bank swizzle (XOR bytes 4..6)

    bf16x8 kf0 = ldb8(kbase + (size_t)(q) * DD + g * 8);
    bf16x8 kf1 = ldb8(kbase + (size_t)(16 + q) * DD + g * 8);
    bf16x8 vf0 = ldb8(vbase + (size_t)(q) * NN + g * 8);
    bf16x8 vf1 = ldb8(vbase + (size_t)(16 + q) * NN + g * 8);
    bf16x8 vf2 = ldb8(vbase + (size_t)(32 + q) * NN + g * 8);

    for (int ph = 0; ph < 12; ++ph) {
        #pragma unroll
        for (int it2 = 0; it2 < 8; ++it2) {
            int m0 = ph * 256 + it2 * 32;
            // prefetch next-iter K and V (tail reads stay inside ws: ok)
            bf16x8 kn0 = ldb8(kbase + (size_t)(m0 + 32 + q) * DD + g * 8);
            bf16x8 kn1 = ldb8(kbase + (size_t)(m0 + 48 + q) * DD + g * 8);
            bf16x8 vn0 = ldb8(vbase + (size_t)(q) * NN + m0 + 32 + g * 8);
            bf16x8 vn1 = ldb8(vbase + (size_t)(16 + q) * NN + m0 + 32 + g * 8);
            bf16x8 vn2 = ldb8(vbase + (size_t)(32 + q) * NN + m0 + 32 + g * 8);

            f32x4 z = {0.f, 0.f, 0.f, 0.f};
            f32x4 s0 = mfma16(kf0, qf, z);
            f32x4 s1 = mfma16(kf1, qf, z);
            short4v pk0, pk1;
            #pragma unroll
            for (int r = 0; r < 4; ++r) {
                pk0[r] = (short)f2bf(exp2f(__builtin_fmaf(s0[r], C, nl2)));
                pk1[r] = (short)f2bf(exp2f(__builtin_fmaf(s1[r], C, nl2)));
            }
            // LDS tile write: p0 at bytes it2*64+8g, p1 at +32 (swizzled)
            unsigned b0 = (unsigned)(it2 * 64 + 8 * g);
            *(short4v*)(prow + (b0 ^ swq)) = pk0;
            *(short4v*)(prow + ((b0 + 32) ^ swq)) = pk1;
            asm volatile("s_waitcnt lgkmcnt(0)" ::: "memory");
            __builtin_amdgcn_sched_barrier(0);
            // PV fragment read: bytes it2*64+16g .. +15 (swizzled, 16B-aligned)
            bf16x8 pf = *(const bf16x8*)(prow + ((unsigned)(it2 * 64 + 16 * g) ^ swq));
            yt0 = mfma16(vf0, pf, yt0);
            yt1 = mfma16(vf1, pf, yt1);
            yt2 = mfma16(vf2, pf, yt2);
            kf0 = kn0; kf1 = kn1; vf0 = vn0; vf1 = vn1; vf2 = vn2;
        }
        // ---- store burst: 16 rows x 1KB contiguous PLAIN (cached) stores ----
        #pragma unroll
        for (int i = 0; i < 16; ++i) {
            unsigned off = ((unsigned)(lane * 8)) ^ ((unsigned)((i & 7) << 4));
            uint2 d = *(const uint2*)(myt + i * 512 + off);
            f32x4 v;
            v[0] = bflo2f(d.x); v[1] = bfhi2f(d.x);
            v[2] = bflo2f(d.y); v[3] = bfhi2f(d.y);
            float* dst = out + (size_t)(bh * NN + qrow + i) * OUTW + ph * 256 + lane * 4;
            *(f32x4*)dst = v;
        }
    }

    // ---- epilogue: y^T frag -> yacc[b*NN+n][h*48 + c] bf16 ----
    int b = bh >> 3, h = bh & 7;
    int nrow = qrow + q;
    unsigned short* yrow = yacc + (size_t)(b * NN + nrow) * KP + h * VW;
    f32x4 yts[3] = { yt0, yt1, yt2 };
    #pragma unroll
    for (int cb = 0; cb < 3; ++cb) {
        short4v pk;
        #pragma unroll
        for (int r = 0; r < 4; ++r) pk[r] = (short)f2bf(yts[cb][r]);
        *(short4v*)(yrow + cb * 16 + 4 * g) = pk;
    }
}

// ---------------------------------------------------------------------------
// proj
// ---------------------------------------------------------------------------
__global__ __launch_bounds__(256) void proj_kernel(
    const unsigned short* __restrict__ yacc, const unsigned short* __restrict__ Wpft,
    const float* __restrict__ bpf, float* __restrict__ out)
{
    int rt = blockIdx.x, ct = blockIdx.y;
    int wv = threadIdx.x >> 6, lane = threadIdx.x & 63;
    int g = lane >> 4, q = lane & 15;
    int row0 = rt * 64 + wv * 16;
    const unsigned short* arow = yacc + (size_t)(row0 + q) * KP + g * 8;
    const unsigned short* b0 = Wpft + (size_t)(ct * 64 + q) * KP + g * 8;
    f32x4 acc[4];
    #pragma unroll
    for (int cb = 0; cb < 4; ++cb) acc[cb] = f32x4{0.f, 0.f, 0.f, 0.f};
    for (int k0 = 0; k0 < KP; k0 += 32) {
        bf16x8 af = ldb8(arow + k0);
        #pragma unroll
        for (int cb = 0; cb < 4; ++cb)
            acc[cb] = mfma16(af, ldb8(b0 + (size_t)cb * 16 * KP + k0), acc[cb]);
    }
    int b = row0 / NN, nb = row0 % NN;
    #pragma unroll
    for (int cb = 0; cb < 4; ++cb) {
        int c2 = ct * 64 + cb * 16 + q;
        float bias = bpf[c2];
        int h = c2 >> 5, c = c2 & 31;
        float* obase = out + (size_t)((b * NH + h) * NN) * OUTW + NN + c;
        #pragma unroll
        for (int r = 0; r < 4; ++r) {
            int n = nb + 4 * g + r;
            __builtin_nontemporal_store(acc[cb][r] + bias, &obase[(size_t)n * OUTW]);
        }
    }
}

// ---------------------------------------------------------------------------
extern "C" void kernel_launch(void* const* d_in, const int* in_sizes, int n_in,
                              void* d_out, int out_size, void* d_ws, size_t ws_size,
                              hipStream_t stream)
{
    (void)in_sizes; (void)n_in; (void)out_size; (void)ws_size;
    const float* x1  = (const float*)d_in[0];
    const float* x2  = (const float*)d_in[1];
    const float* Wq  = (const float*)d_in[2];
    const float* Wkv = (const float*)d_in[3];
    const float* Wpf = (const float*)d_in[4];
    const float* bpf = (const float*)d_in[5];
    float* out = (float*)d_out;
    char* ws = (char*)d_ws;

    unsigned short* x1b  = (unsigned short*)(ws + 0);
    unsigned short* x2b  = (unsigned short*)(ws + 3145728);
    unsigned short* Wt   = (unsigned short*)(ws + 6291456);
    unsigned short* Wpft = (unsigned short*)(ws + 6684672);
    unsigned short* qbh  = (unsigned short*)(ws + 6881280);
    unsigned short* kbh  = (unsigned short*)(ws + 10027008);
    unsigned short* v2pT = (unsigned short*)(ws + 13172736);
    unsigned short* yacc = (unsigned short*)(ws + 17891328);

    prep_kernel<<<16512, 256, 0, stream>>>(x1, x2, Wq, Wkv, Wpf, x1b, x2b, Wt, Wpft, v2pT);
    qkv_kernel<<<dim3(96, 12), 256, 0, stream>>>(x1b, x2b, Wt, qbh, kbh, v2pT);
    attn_kernel<<<768, 256, 0, stream>>>(qbh, kbh, v2pT, out, yacc);
    proj_kernel<<<dim3(96, 4), 256, 0, stream>>>(yacc, Wpft, bpf, out);
}

// Round 10
// 258.631 us; speedup vs baseline: 1.1033x; 1.1033x over previous
//
#include <hip/hip_runtime.h>
#include <hip/hip_bf16.h>
#include <cstdint>
#include <cstddef>

#define NB 2
#define NH 8
#define BHN 16          // NB*NH
#define NN 3072         // tokens
#define CC 256          // channels
#define DD 32           // head dim
#define OUTW 3104       // NN + DD
#define VW 48           // padded v2p width (38 -> 48)
#define KP 384          // NH*VW, padded K for proj GEMM

typedef __attribute__((ext_vector_type(8))) __bf16 bf16x8;
typedef __attribute__((ext_vector_type(4))) short short4v;
typedef __attribute__((ext_vector_type(4))) float f32x4;

static __device__ __forceinline__ unsigned short f2bf(float f) {
    __hip_bfloat16 h = __float2bfloat16(f);
    return *reinterpret_cast<unsigned short*>(&h);
}

static __device__ __forceinline__ bf16x8 ldb8(const unsigned short* p) {
    return *(const bf16x8*)p;
}

static __device__ __forceinline__ f32x4 mfma16(bf16x8 a, bf16x8 b, f32x4 c) {
    return __builtin_amdgcn_mfma_f32_16x16x32_bf16(a, b, c, 0, 0, 0);
}

static __device__ __forceinline__ float bfhi2f(unsigned u) {
    union { unsigned u; float f; } v; v.u = u & 0xffff0000u; return v.f;
}
static __device__ __forceinline__ float bflo2f(unsigned u) {
    union { unsigned u; float f; } v; v.u = u << 16; return v.f;
}

// ---------------------------------------------------------------------------
// prep
// ---------------------------------------------------------------------------
__global__ __launch_bounds__(256) void prep_kernel(
    const float* __restrict__ x1, const float* __restrict__ x2,
    const float* __restrict__ Wq, const float* __restrict__ Wkv,
    const float* __restrict__ Wpf,
    unsigned short* __restrict__ x1b, unsigned short* __restrict__ x2b,
    unsigned short* __restrict__ Wt, unsigned short* __restrict__ Wpft,
    unsigned short* __restrict__ v2pT)
{
    int i = blockIdx.x * 256 + threadIdx.x;
    const int S_X = NB * NN * CC;
    if (i < S_X) { x1b[i] = f2bf(x1[i]); return; }
    i -= S_X;
    if (i < S_X) { x2b[i] = f2bf(x2[i]); return; }
    i -= S_X;
    const int S_WT = 768 * CC;
    if (i < S_WT) {
        int j = i >> 8, kk = i & 255;
        float w = (j < 256) ? Wq[kk * 256 + j] : Wkv[kk * 512 + (j - 256)];
        Wt[i] = f2bf(w);
        return;
    }
    i -= S_WT;
    const int S_WP = 256 * KP;
    if (i < S_WP) {
        int c2 = i / KP, t = i - c2 * KP;
        int h = t / VW, cc = t - h * VW;
        unsigned short v = 0;
        if (cc < 38) v = f2bf(Wpf[(h * 38 + cc) * 256 + c2]);
        Wpft[i] = v;
        return;
    }
    i -= S_WP;
    const int S_POS = BHN * 16 * NN;
    if (i < S_POS) {
        int n = i % NN;
        int r = i / NN;
        int bh = r >> 4;
        int c = (r & 15) + 32;
        float val = 0.f;
        if (c < 38) {
            float p3 = -1.f + 2.f * (float)(n % 48) / 47.f;
            float p4 = -1.f + 2.f * (float)(n / 48) / 63.f;
            float pv[6] = { p3 * p3, p4 * p4, p3 * p4, p3, p4, 1.f };
            val = pv[c - 32];
        }
        v2pT[((size_t)bh * VW + c) * NN + n] = f2bf(val);
    }
}

// ---------------------------------------------------------------------------
// qkv
// ---------------------------------------------------------------------------
__global__ __launch_bounds__(256) void qkv_kernel(
    const unsigned short* __restrict__ x1b, const unsigned short* __restrict__ x2b,
    const unsigned short* __restrict__ Wt,
    unsigned short* __restrict__ qbh, unsigned short* __restrict__ kbh,
    unsigned short* __restrict__ v2pT)
{
    int rt = blockIdx.x, ct = blockIdx.y;
    int wv = threadIdx.x >> 6, lane = threadIdx.x & 63;
    int g = lane >> 4, q = lane & 15;
    int row0 = rt * 64 + wv * 16;
    const unsigned short* A = (ct < 4) ? x1b : x2b;
    const unsigned short* arow = A + (size_t)(row0 + q) * CC + g * 8;
    const unsigned short* brow = Wt + (size_t)(ct * 64 + q) * CC + g * 8;
    f32x4 acc[4];
    #pragma unroll
    for (int cb = 0; cb < 4; ++cb) acc[cb] = f32x4{0.f, 0.f, 0.f, 0.f};
    for (int k0 = 0; k0 < CC; k0 += 32) {
        bf16x8 af = ldb8(arow + k0);
        #pragma unroll
        for (int cb = 0; cb < 4; ++cb)
            acc[cb] = mfma16(af, ldb8(brow + (size_t)cb * 16 * CC + k0), acc[cb]);
    }
    int b = row0 / NN, nb = row0 % NN;
    #pragma unroll
    for (int cb = 0; cb < 4; ++cb) {
        int jj = ct * 64 + cb * 16 + q;
        #pragma unroll
        for (int r = 0; r < 4; ++r) {
            int n = nb + 4 * g + r;
            unsigned short bv = f2bf(acc[cb][r]);
            if (jj < 256) {
                int h = jj >> 5, c = jj & 31;
                qbh[(size_t)((b * NH + h) * NN + n) * DD + c] = bv;
            } else if (jj < 512) {
                int jk = jj - 256; int h = jk >> 5, c = jk & 31;
                kbh[(size_t)((b * NH + h) * NN + n) * DD + c] = bv;
            } else {
                int jv = jj - 512; int h = jv >> 5, c = jv & 31;
                v2pT[(size_t)((b * NH + h) * VW + c) * NN + n] = bv;
            }
        }
    }
}

// ---------------------------------------------------------------------------
// fused attention v10: block = 16 q-rows of one bh; 4 waves split m.
// Pass A: each wave sums exp over a contiguous m-quarter; LDS reduce -> l.
// Pass B: 3 phases of 1024 m. Within a phase each wave owns an interleaved
// 256-col slice of a SHARED [16][1024] bf16 LDS tile (wave-private writes +
// own-slice PV reads, same relayout as R5). After a barrier, each wave
// NT-stores 4 ADJACENT rows x 4KB CONTIGUOUS f32 (tests page-granularity
// theory at matched occupancy: 4 blocks/CU = 16 waves/CU).
// y^T partial per wave; one-time cross-wave LDS reduce at the end.
// ---------------------------------------------------------------------------
__global__ __launch_bounds__(256) void attn_kernel(
    const unsigned short* __restrict__ qbh, const unsigned short* __restrict__ kbh,
    const unsigned short* __restrict__ v2pT,
    float* __restrict__ out, unsigned short* __restrict__ yacc)
{
    __shared__ unsigned short tile[16][1024];   // 32 KB shared, wave-private 512B slices
    __shared__ float lred[4][16];
    const float C = 0.17677669529663687f * 1.4426950408889634f;  // scale*log2e

    // XCD-bijective swizzle: 3072 % 8 == 0
    int id = blockIdx.x;
    int xcd = id & 7;
    int slot = id >> 3;                 // 0..383
    int bh = xcd * 2 + (slot & 1);      // 0..15
    int tl = slot >> 1;                 // 0..191
    int qrow = tl * 16;

    int wv = threadIdx.x >> 6, lane = threadIdx.x & 63;
    int g = lane >> 4, q = lane & 15;

    bf16x8 qf = ldb8(qbh + (size_t)(bh * NN + qrow + q) * DD + g * 8);
    const unsigned short* kbase = kbh + (size_t)bh * NN * DD;
    const unsigned short* vbase = v2pT + (size_t)bh * VW * NN;

    // ---- pass A: partial row sums of exp over this wave's m-quarter ----
    float l = 0.f;
    {
        int mb = wv * 768;
        bf16x8 kf0 = ldb8(kbase + (size_t)(mb + q) * DD + g * 8);
        bf16x8 kf1 = ldb8(kbase + (size_t)(mb + 16 + q) * DD + g * 8);
        for (int it = 0; it < 24; ++it) {
            int m0 = mb + it * 32;
            bf16x8 kn0 = ldb8(kbase + (size_t)(m0 + 32 + q) * DD + g * 8);
            bf16x8 kn1 = ldb8(kbase + (size_t)(m0 + 48 + q) * DD + g * 8);
            f32x4 z = {0.f, 0.f, 0.f, 0.f};
            f32x4 s0 = mfma16(kf0, qf, z);
            f32x4 s1 = mfma16(kf1, qf, z);
            #pragma unroll
            for (int r = 0; r < 4; ++r)
                l += exp2f(s0[r] * C) + exp2f(s1[r] * C);
            kf0 = kn0; kf1 = kn1;
        }
    }
    l += __shfl_xor(l, 16, 64);
    l += __shfl_xor(l, 32, 64);
    if (lane < 16) lred[wv][q] = l;
    __syncthreads();
    float nl2 = -__log2f(lred[0][q] + lred[1][q] + lred[2][q] + lred[3][q]);

    // ---- pass B ----
    f32x4 yt0 = {0.f,0.f,0.f,0.f}, yt1 = yt0, yt2 = yt0;
    char* tbase = (char*)&tile[0][0];
    char* prowc = tbase + q * 2048;              // this thread's write row
    unsigned swq = (unsigned)((q & 7) << 4);     // bank swizzle (XOR bytes 4..6)
    int wb = wv * 512;                           // wave's byte slice within a row

    for (int ph = 0; ph < 3; ++ph) {
        int pbase = ph * 1024 + wv * 256;
        bf16x8 kf0 = ldb8(kbase + (size_t)(pbase + q) * DD + g * 8);
        bf16x8 kf1 = ldb8(kbase + (size_t)(pbase + 16 + q) * DD + g * 8);
        bf16x8 vf0 = ldb8(vbase + (size_t)(q) * NN + pbase + g * 8);
        bf16x8 vf1 = ldb8(vbase + (size_t)(16 + q) * NN + pbase + g * 8);
        bf16x8 vf2 = ldb8(vbase + (size_t)(32 + q) * NN + pbase + g * 8);
        #pragma unroll
        for (int it2 = 0; it2 < 8; ++it2) {
            int m0 = pbase + it2 * 32;
            // next-iter m (next slice start when crossing a phase; tail reads stay in ws)
            int mn = (it2 < 7) ? (m0 + 32) : ((ph + 1) * 1024 + wv * 256);
            bf16x8 kn0 = ldb8(kbase + (size_t)(mn + q) * DD + g * 8);
            bf16x8 kn1 = ldb8(kbase + (size_t)(mn + 16 + q) * DD + g * 8);
            bf16x8 vn0 = ldb8(vbase + (size_t)(q) * NN + mn + g * 8);
            bf16x8 vn1 = ldb8(vbase + (size_t)(16 + q) * NN + mn + g * 8);
            bf16x8 vn2 = ldb8(vbase + (size_t)(32 + q) * NN + mn + g * 8);

            f32x4 z = {0.f, 0.f, 0.f, 0.f};
            f32x4 s0 = mfma16(kf0, qf, z);
            f32x4 s1 = mfma16(kf1, qf, z);
            short4v pk0, pk1;
            #pragma unroll
            for (int r = 0; r < 4; ++r) {
                pk0[r] = (short)f2bf(exp2f(__builtin_fmaf(s0[r], C, nl2)));
                pk1[r] = (short)f2bf(exp2f(__builtin_fmaf(s1[r], C, nl2)));
            }
            unsigned b0 = (unsigned)(wb + it2 * 64 + 8 * g);
            *(short4v*)(prowc + (b0 ^ swq)) = pk0;
            *(short4v*)(prowc + ((b0 + 32) ^ swq)) = pk1;
            asm volatile("s_waitcnt lgkmcnt(0)" ::: "memory");
            __builtin_amdgcn_sched_barrier(0);
            bf16x8 pf = *(const bf16x8*)(prowc + ((unsigned)(wb + it2 * 64 + 16 * g) ^ swq));
            yt0 = mfma16(vf0, pf, yt0);
            yt1 = mfma16(vf1, pf, yt1);
            yt2 = mfma16(vf2, pf, yt2);
            kf0 = kn0; kf1 = kn1; vf0 = vn0; vf1 = vn1; vf2 = vn2;
        }
        __syncthreads();   // tile complete for this phase
        // ---- cooperative store: wave wv writes rows 4wv..4wv+3, 4KB contiguous each ----
        #pragma unroll
        for (int j = 0; j < 4; ++j) {
            int r = wv * 4 + j;
            const char* rsrc = tbase + r * 2048;
            unsigned swr = (unsigned)((r & 7) << 4);
            float* dst = out + (size_t)(bh * NN + qrow + r) * OUTW + ph * 1024 + lane * 4;
            #pragma unroll
            for (int st = 0; st < 4; ++st) {
                unsigned off = ((unsigned)(st * 512 + lane * 8)) ^ swr;
                unsigned long long d = *(const unsigned long long*)(rsrc + off);
                unsigned dlo = (unsigned)d, dhi = (unsigned)(d >> 32);
                f32x4 v;
                v[0] = bflo2f(dlo); v[1] = bfhi2f(dlo);
                v[2] = bflo2f(dhi); v[3] = bfhi2f(dhi);
                __builtin_nontemporal_store(v, (f32x4*)(dst + st * 256));
            }
        }
        __syncthreads();   // LDS reads done (stores depend on them); safe to refill
    }

    // ---- cross-wave y^T reduce (reuse tile as float scratch) ----
    float* yl = (float*)tbase;       // [4][48][17] floats = 13056 B <= 32 KB
    {
        f32x4 yts[3] = { yt0, yt1, yt2 };
        #pragma unroll
        for (int cb = 0; cb < 3; ++cb)
            #pragma unroll
            for (int r = 0; r < 4; ++r)
                yl[(wv * 48 + cb * 16 + 4 * g + r) * 17 + q] = yts[cb][r];
    }
    __syncthreads();
    {
        int t = threadIdx.x;
        if (t < 192) {
            int c0 = (t >> 4) << 2;      // 0,4,...,44
            int qq = t & 15;
            int b = bh >> 3, h = bh & 7;
            short4v pk;
            #pragma unroll
            for (int rr = 0; rr < 4; ++rr) {
                int c = c0 + rr;
                float s = yl[(0 * 48 + c) * 17 + qq] + yl[(1 * 48 + c) * 17 + qq]
                        + yl[(2 * 48 + c) * 17 + qq] + yl[(3 * 48 + c) * 17 + qq];
                pk[rr] = (short)f2bf(s);
            }
            *(short4v*)(yacc + (size_t)(b * NN + qrow + qq) * KP + h * VW + c0) = pk;
        }
    }
}

// ---------------------------------------------------------------------------
// proj
// ---------------------------------------------------------------------------
__global__ __launch_bounds__(256) void proj_kernel(
    const unsigned short* __restrict__ yacc, const unsigned short* __restrict__ Wpft,
    const float* __restrict__ bpf, float* __restrict__ out)
{
    int rt = blockIdx.x, ct = blockIdx.y;
    int wv = threadIdx.x >> 6, lane = threadIdx.x & 63;
    int g = lane >> 4, q = lane & 15;
    int row0 = rt * 64 + wv * 16;
    const unsigned short* arow = yacc + (size_t)(row0 + q) * KP + g * 8;
    const unsigned short* b0 = Wpft + (size_t)(ct * 64 + q) * KP + g * 8;
    f32x4 acc[4];
    #pragma unroll
    for (int cb = 0; cb < 4; ++cb) acc[cb] = f32x4{0.f, 0.f, 0.f, 0.f};
    for (int k0 = 0; k0 < KP; k0 += 32) {
        bf16x8 af = ldb8(arow + k0);
        #pragma unroll
        for (int cb = 0; cb < 4; ++cb)
            acc[cb] = mfma16(af, ldb8(b0 + (size_t)cb * 16 * KP + k0), acc[cb]);
    }
    int b = row0 / NN, nb = row0 % NN;
    #pragma unroll
    for (int cb = 0; cb < 4; ++cb) {
        int c2 = ct * 64 + cb * 16 + q;
        float bias = bpf[c2];
        int h = c2 >> 5, c = c2 & 31;
        float* obase = out + (size_t)((b * NH + h) * NN) * OUTW + NN + c;
        #pragma unroll
        for (int r = 0; r < 4; ++r) {
            int n = nb + 4 * g + r;
            __builtin_nontemporal_store(acc[cb][r] + bias, &obase[(size_t)n * OUTW]);
        }
    }
}

// ---------------------------------------------------------------------------
extern "C" void kernel_launch(void* const* d_in, const int* in_sizes, int n_in,
                              void* d_out, int out_size, void* d_ws, size_t ws_size,
                              hipStream_t stream)
{
    (void)in_sizes; (void)n_in; (void)out_size; (void)ws_size;
    const float* x1  = (const float*)d_in[0];
    const float* x2  = (const float*)d_in[1];
    const float* Wq  = (const float*)d_in[2];
    const float* Wkv = (const float*)d_in[3];
    const float* Wpf = (const float*)d_in[4];
    const float* bpf = (const float*)d_in[5];
    float* out = (float*)d_out;
    char* ws = (char*)d_ws;

    unsigned short* x1b  = (unsigned short*)(ws + 0);
    unsigned short* x2b  = (unsigned short*)(ws + 3145728);
    unsigned short* Wt   = (unsigned short*)(ws + 6291456);
    unsigned short* Wpft = (unsigned short*)(ws + 6684672);
    unsigned short* qbh  = (unsigned short*)(ws + 6881280);
    unsigned short* kbh  = (unsigned short*)(ws + 10027008);
    unsigned short* v2pT = (unsigned short*)(ws + 13172736);
    unsigned short* yacc = (unsigned short*)(ws + 17891328);

    prep_kernel<<<16512, 256, 0, stream>>>(x1, x2, Wq, Wkv, Wpf, x1b, x2b, Wt, Wpft, v2pT);
    qkv_kernel<<<dim3(96, 12), 256, 0, stream>>>(x1b, x2b, Wt, qbh, kbh, v2pT);
    attn_kernel<<<3072, 256, 0, stream>>>(qbh, kbh, v2pT, out, yacc);
    proj_kernel<<<dim3(96, 4), 256, 0, stream>>>(yacc, Wpft, bpf, out);
}